// Round 3
// baseline (797.979 us; speedup 1.0000x reference)
//
#include <hip/hip_runtime.h>
#include <stddef.h>

// Sizes (fixed by the problem)
#define BB   128      // batch
#define TT   512      // time
#define VV   32000    // vocab
#define DD   300      // emb dim
#define HH   128      // hidden
#define G3   384      // 3*H
#define NC   768      // 2*3*H (fwd+bwd projected gates)

// ---------------------------------------------------------------------------
// Kernel 1: P[v][g] = emb[v][:] @ Wcat[:, g] + b_i[g]
//   cols 0..383   <- W_f, b_f[0]
//   cols 384..767 <- W_b, b_b[0]
// fp32 tiled GEMM: 128x128 tile, K-tile 12 (25 iters, 300 = 25*12),
// 256 threads, 8x8 micro-tile. A staged transposed [k][row] so micro reads
// are contiguous b128; B staged with a +4-per-32 column skew to kill the
// 4-way bank conflict on the b-fragment reads.
// ---------------------------------------------------------------------------
__global__ __launch_bounds__(256) void proj_kernel(
    const float* __restrict__ emb,
    const float* __restrict__ Wf, const float* __restrict__ Wb,
    const float* __restrict__ bf, const float* __restrict__ bb,
    float* __restrict__ P)
{
    __shared__ float As[12 * 128];       // [k][row]
    __shared__ float Bs[12 * 140];       // [k][skewed col], stride 140

    const int m0 = blockIdx.x * 128;     // vocab-row tile
    const int n0 = blockIdx.y * 128;     // output-col tile

    const float* Wsrc;
    const float* bsrc;
    int cb;
    if (n0 < G3) { Wsrc = Wf; bsrc = bf; cb = n0; }
    else         { Wsrc = Wb; bsrc = bb; cb = n0 - G3; }

    const int t  = threadIdx.x;
    const int tx = t & 15;               // col group (8 cols each)
    const int ty = t >> 4;               // row group (8 rows each)

    float acc[8][8];
    #pragma unroll
    for (int i = 0; i < 8; ++i)
        #pragma unroll
        for (int j = 0; j < 8; ++j) acc[i][j] = 0.f;

    // skewed read base for B fragments: col' = col + (col>>5)*4, col = tx*8
    const int bread = tx * 8 + ((tx >> 2) << 2);

    for (int kt = 0; kt < 25; ++kt) {
        const int kbase = kt * 12;

        // ---- stage A (128 rows x 12 k) transposed into As[k][row] ----
        {
            int row = t & 127, ch = t >> 7;               // ch 0..1 covers k 0..7
            float4 v = *(const float4*)(emb + (size_t)(m0 + row) * DD + kbase + ch * 4);
            As[(ch * 4 + 0) * 128 + row] = v.x;
            As[(ch * 4 + 1) * 128 + row] = v.y;
            As[(ch * 4 + 2) * 128 + row] = v.z;
            As[(ch * 4 + 3) * 128 + row] = v.w;
            if (t < 128) {                                // k 8..11 for all rows
                int row2 = t;
                float4 v2 = *(const float4*)(emb + (size_t)(m0 + row2) * DD + kbase + 8);
                As[ 8 * 128 + row2] = v2.x;
                As[ 9 * 128 + row2] = v2.y;
                As[10 * 128 + row2] = v2.z;
                As[11 * 128 + row2] = v2.w;
            }
        }
        // ---- stage B (12 k x 128 cols) into Bs[k][skew(col)] ----
        {
            int kr = t >> 5, cg = t & 31, col = cg * 4;
            float4 w = *(const float4*)(Wsrc + (size_t)(kbase + kr) * G3 + cb + col);
            int sc = col + ((col >> 5) << 2);
            *(float4*)&Bs[kr * 140 + sc] = w;
            if (t < 128) {                                // k rows 8..11
                int kr2 = 8 + (t >> 5), cg2 = t & 31, col2 = cg2 * 4;
                float4 w2 = *(const float4*)(Wsrc + (size_t)(kbase + kr2) * G3 + cb + col2);
                int sc2 = col2 + ((col2 >> 5) << 2);
                *(float4*)&Bs[kr2 * 140 + sc2] = w2;
            }
        }
        __syncthreads();

        #pragma unroll
        for (int kk = 0; kk < 12; ++kk) {
            const float4* ap = (const float4*)&As[kk * 128 + ty * 8];
            const float4* bp = (const float4*)&Bs[kk * 140 + bread];
            float4 a0 = ap[0], a1 = ap[1];
            float4 b0 = bp[0], b1 = bp[1];
            float a[8]   = {a0.x,a0.y,a0.z,a0.w,a1.x,a1.y,a1.z,a1.w};
            float bfr[8] = {b0.x,b0.y,b0.z,b0.w,b1.x,b1.y,b1.z,b1.w};
            #pragma unroll
            for (int i = 0; i < 8; ++i)
                #pragma unroll
                for (int j = 0; j < 8; ++j)
                    acc[i][j] += a[i] * bfr[j];
        }
        __syncthreads();
    }

    // ---- epilogue: + input bias, store ----
    float bias[8];
    #pragma unroll
    for (int j = 0; j < 8; ++j) bias[j] = bsrc[cb + tx * 8 + j];

    #pragma unroll
    for (int i = 0; i < 8; ++i) {
        int row = m0 + ty * 8 + i;
        float4 o0 = { acc[i][0] + bias[0], acc[i][1] + bias[1],
                      acc[i][2] + bias[2], acc[i][3] + bias[3] };
        float4 o1 = { acc[i][4] + bias[4], acc[i][5] + bias[5],
                      acc[i][6] + bias[6], acc[i][7] + bias[7] };
        float* dst = P + (size_t)row * NC + n0 + tx * 8;
        *(float4*)dst       = o0;
        *(float4*)(dst + 4) = o1;
    }
}

// ---------------------------------------------------------------------------
// Kernel 2: the GRU scan. grid = (128 batch, 2 directions), 384 threads.
// Thread g owns output column g; U[:,g] lives in 128 VGPRs. h broadcast via
// LDS (wave-uniform ds_read_b128). One block per CU (256 blocks total).
// Backward direction runs time-reversed and writes out[:, t, 128:256].
// Barrier discipline: barrier1 separates {sr/xh/rh writes} from reads;
// barrier2 separates the hcur[g] update from the next iteration's reads.
// ---------------------------------------------------------------------------
__global__ __launch_bounds__(384, 2) void scan_kernel(
    const int*   __restrict__ tokens,
    const float* __restrict__ state_f, const float* __restrict__ state_b,
    const float* __restrict__ Uf, const float* __restrict__ Ub,
    const float* __restrict__ bf, const float* __restrict__ bb,
    const float* __restrict__ P,
    float* __restrict__ out)
{
    const int b = blockIdx.x;
    const int d = blockIdx.y;            // 0 = fwd, 1 = bwd
    const int g = threadIdx.x;           // 0..383

    const float* U  = d ? Ub : Uf;
    const float* bv = d ? bb : bf;
    const float* st = d ? state_b : state_f;
    const int    cb = d ? G3 : 0;        // column base into P

    __shared__ __align__(16) float hcur[HH];
    __shared__ float sr[HH], xh_s[HH], rh_s[HH];

    // U column -> registers (coalesced: consecutive g -> consecutive addr)
    float u[HH];
    #pragma unroll
    for (int k = 0; k < HH; ++k) u[k] = U[(size_t)k * G3 + g];

    const float brec = bv[G3 + g];       // recurrent bias b[1][g]

    float hreg = 0.f;
    if (g < HH) { hreg = st[b * HH + g]; hcur[g] = hreg; }
    __syncthreads();

    // prefetch P row for step 0
    int tfirst = d ? (TT - 1) : 0;
    float xp_next = P[(size_t)tokens[b * TT + tfirst] * NC + cb + g];

    for (int i = 0; i < TT; ++i) {
        const int tcur = d ? (TT - 1 - i) : i;
        const float xp = xp_next;
        if (i + 1 < TT) {
            int tn = d ? (TT - 2 - i) : (i + 1);
            xp_next = P[(size_t)tokens[b * TT + tn] * NC + cb + g];
        }

        // rec[g] = b_r[g] + sum_k h[k] * U[k][g]  (4 accs break dep chain)
        float a0 = brec, a1 = 0.f, a2 = 0.f, a3 = 0.f;
        const float4* h4 = (const float4*)hcur;
        #pragma unroll
        for (int k4 = 0; k4 < HH / 4; ++k4) {
            float4 hv = h4[k4];
            a0 += hv.x * u[k4 * 4 + 0];
            a1 += hv.y * u[k4 * 4 + 1];
            a2 += hv.z * u[k4 * 4 + 2];
            a3 += hv.w * u[k4 * 4 + 3];
        }
        const float rec = (a0 + a1) + (a2 + a3);

        float my_sz = 0.f;
        if (g < HH)            my_sz = rec + xp;          // z-gate pre-act
        else if (g < 2 * HH)   sr[g - HH] = rec + xp;     // r-gate pre-act
        else { rh_s[g - 2*HH] = rec; xh_s[g - 2*HH] = xp; }
        __syncthreads();                                  // barrier1

        if (g < HH) {
            float z = 1.f / (1.f + expf(-my_sz));
            float r = 1.f / (1.f + expf(-sr[g]));
            float ph = xh_s[g] + r * rh_s[g];
            ph = fminf(fmaxf(ph, -15.f), 15.f);
            float e  = expf(-2.f * ph);
            float hh = (1.f - e) / (1.f + e);             // tanh
            float hn = z * hreg + (1.f - z) * hh;
            hreg = hn;
            hcur[g] = hn;
            out[((size_t)b * TT + tcur) * 256 + d * HH + g] = hn;
        }
        __syncthreads();                                  // barrier2
    }

    if (g < HH) {
        // final states: [B*T*256 | h_f (B*H) | h_b (B*H)]
        out[(size_t)BB * TT * 256 + (size_t)d * BB * HH + b * HH + g] = hreg;
    }
}

// ---------------------------------------------------------------------------
extern "C" void kernel_launch(void* const* d_in, const int* in_sizes, int n_in,
                              void* d_out, int out_size, void* d_ws, size_t ws_size,
                              hipStream_t stream)
{
    const int*   tokens  = (const int*)  d_in[0];
    const float* state_f = (const float*)d_in[1];
    const float* state_b = (const float*)d_in[2];
    const float* emb     = (const float*)d_in[3];
    const float* W_f     = (const float*)d_in[4];
    const float* U_f     = (const float*)d_in[5];
    const float* b_f     = (const float*)d_in[6];
    const float* W_b     = (const float*)d_in[7];
    const float* U_b     = (const float*)d_in[8];
    const float* b_b     = (const float*)d_in[9];
    float*       out     = (float*)d_out;

    float* P = (float*)d_ws;   // needs 32000*768*4 = 98.3 MB of workspace

    dim3 gp(VV / 128, NC / 128);           // 250 x 6
    proj_kernel<<<gp, 256, 0, stream>>>(emb, W_f, W_b, b_f, b_b, P);

    dim3 gs(BB, 2);                         // 128 batch x 2 directions
    scan_kernel<<<gs, 384, 0, stream>>>(tokens, state_f, state_b,
                                        U_f, U_b, b_f, b_b, P, out);
}

// Round 4
// 716.317 us; speedup vs baseline: 1.1140x; 1.1140x over previous
//
#include <hip/hip_runtime.h>
#include <stddef.h>

// Sizes (fixed by the problem)
#define BB   128      // batch
#define TT   512      // time
#define VV   32000    // vocab
#define DD   300      // emb dim
#define HH   128      // hidden
#define G3   384      // 3*H
#define NC   768      // 2*3*H (fwd+bwd projected gates)

// ---------------------------------------------------------------------------
// Kernel 1: P[v][g] = emb[v][:] @ Wcat[:, g] + b_i[g]   (unchanged, ~231 us)
// ---------------------------------------------------------------------------
__global__ __launch_bounds__(256) void proj_kernel(
    const float* __restrict__ emb,
    const float* __restrict__ Wf, const float* __restrict__ Wb,
    const float* __restrict__ bf, const float* __restrict__ bb,
    float* __restrict__ P)
{
    __shared__ float As[12 * 128];       // [k][row]
    __shared__ float Bs[12 * 140];       // [k][skewed col], stride 140

    const int m0 = blockIdx.x * 128;     // vocab-row tile
    const int n0 = blockIdx.y * 128;     // output-col tile

    const float* Wsrc;
    const float* bsrc;
    int cb;
    if (n0 < G3) { Wsrc = Wf; bsrc = bf; cb = n0; }
    else         { Wsrc = Wb; bsrc = bb; cb = n0 - G3; }

    const int t  = threadIdx.x;
    const int tx = t & 15;               // col group (8 cols each)
    const int ty = t >> 4;               // row group (8 rows each)

    float acc[8][8];
    #pragma unroll
    for (int i = 0; i < 8; ++i)
        #pragma unroll
        for (int j = 0; j < 8; ++j) acc[i][j] = 0.f;

    const int bread = tx * 8 + ((tx >> 2) << 2);

    for (int kt = 0; kt < 25; ++kt) {
        const int kbase = kt * 12;

        {
            int row = t & 127, ch = t >> 7;               // ch 0..1 covers k 0..7
            float4 v = *(const float4*)(emb + (size_t)(m0 + row) * DD + kbase + ch * 4);
            As[(ch * 4 + 0) * 128 + row] = v.x;
            As[(ch * 4 + 1) * 128 + row] = v.y;
            As[(ch * 4 + 2) * 128 + row] = v.z;
            As[(ch * 4 + 3) * 128 + row] = v.w;
            if (t < 128) {                                // k 8..11 for all rows
                int row2 = t;
                float4 v2 = *(const float4*)(emb + (size_t)(m0 + row2) * DD + kbase + 8);
                As[ 8 * 128 + row2] = v2.x;
                As[ 9 * 128 + row2] = v2.y;
                As[10 * 128 + row2] = v2.z;
                As[11 * 128 + row2] = v2.w;
            }
        }
        {
            int kr = t >> 5, cg = t & 31, col = cg * 4;
            float4 w = *(const float4*)(Wsrc + (size_t)(kbase + kr) * G3 + cb + col);
            int sc = col + ((col >> 5) << 2);
            *(float4*)&Bs[kr * 140 + sc] = w;
            if (t < 128) {                                // k rows 8..11
                int kr2 = 8 + (t >> 5), cg2 = t & 31, col2 = cg2 * 4;
                float4 w2 = *(const float4*)(Wsrc + (size_t)(kbase + kr2) * G3 + cb + col2);
                int sc2 = col2 + ((col2 >> 5) << 2);
                *(float4*)&Bs[kr2 * 140 + sc2] = w2;
            }
        }
        __syncthreads();

        #pragma unroll
        for (int kk = 0; kk < 12; ++kk) {
            const float4* ap = (const float4*)&As[kk * 128 + ty * 8];
            const float4* bp = (const float4*)&Bs[kk * 140 + bread];
            float4 a0 = ap[0], a1 = ap[1];
            float4 b0 = bp[0], b1 = bp[1];
            float a[8]   = {a0.x,a0.y,a0.z,a0.w,a1.x,a1.y,a1.z,a1.w};
            float bfr[8] = {b0.x,b0.y,b0.z,b0.w,b1.x,b1.y,b1.z,b1.w};
            #pragma unroll
            for (int i = 0; i < 8; ++i)
                #pragma unroll
                for (int j = 0; j < 8; ++j)
                    acc[i][j] += a[i] * bfr[j];
        }
        __syncthreads();
    }

    float bias[8];
    #pragma unroll
    for (int j = 0; j < 8; ++j) bias[j] = bsrc[cb + tx * 8 + j];

    #pragma unroll
    for (int i = 0; i < 8; ++i) {
        int row = m0 + ty * 8 + i;
        float4 o0 = { acc[i][0] + bias[0], acc[i][1] + bias[1],
                      acc[i][2] + bias[2], acc[i][3] + bias[3] };
        float4 o1 = { acc[i][4] + bias[4], acc[i][5] + bias[5],
                      acc[i][6] + bias[6], acc[i][7] + bias[7] };
        float* dst = P + (size_t)row * NC + n0 + tx * 8;
        *(float4*)dst       = o0;
        *(float4*)(dst + 4) = o1;
    }
}

// ---------------------------------------------------------------------------
// Kernel 2: GRU scan. grid = (128 batch, 2 dirs), 384 threads, 1 block/CU.
// Thread g owns gate-column g; U[:,g] in VGPRs (the point of
// __launch_bounds__(384) with no min-wave constraint: ~170 VGPRs available,
// u[128]+misc fits — Round 3 showed (384,2) pushed u[] into AGPR copies:
// VGPR_Count=88, VALU cy/step 2.5x theoretical).
// Raw barriers (lgkmcnt-only) avoid __syncthreads' vmcnt(0) drain of the
// P prefetch (B1) and the out store (B2) every step.
// ---------------------------------------------------------------------------
#define BAR() asm volatile("s_waitcnt lgkmcnt(0)\n\ts_barrier" ::: "memory")

__global__ __launch_bounds__(384) void scan_kernel(
    const int*   __restrict__ tokens,
    const float* __restrict__ state_f, const float* __restrict__ state_b,
    const float* __restrict__ Uf, const float* __restrict__ Ub,
    const float* __restrict__ bf, const float* __restrict__ bb,
    const float* __restrict__ P,
    float* __restrict__ out)
{
    const int b = blockIdx.x;
    const int d = blockIdx.y;            // 0 = fwd, 1 = bwd
    const int g = threadIdx.x;           // 0..383

    const float* U  = d ? Ub : Uf;
    const float* bv = d ? bb : bf;
    const float* st = d ? state_b : state_f;
    const int    cb = d ? G3 : 0;        // column base into P

    __shared__ __align__(16) float hcur[HH];
    __shared__ float sr[HH], xh_s[HH], rh_s[HH];

    // U column -> registers (coalesced: consecutive g -> consecutive addr)
    float u[HH];
    #pragma unroll
    for (int k = 0; k < HH; ++k) u[k] = U[(size_t)k * G3 + g];

    const float brec = bv[G3 + g];       // recurrent bias b[1][g]

    float hreg = 0.f;
    if (g < HH) { hreg = st[b * HH + g]; hcur[g] = hreg; }
    __syncthreads();

    const int tok_base = b * TT;
    // prefetch P row for step 0
    int tfirst = d ? (TT - 1) : 0;
    float xp_next = P[(size_t)tokens[tok_base + tfirst] * NC + cb + g];

    for (int i = 0; i < TT; ++i) {
        const int tcur = d ? (TT - 1 - i) : i;
        const float xp = xp_next;
        {   // branchless prefetch (last iter re-reads same row; harmless)
            int in1 = (i + 1 < TT) ? (i + 1) : i;
            int tn  = d ? (TT - 1 - in1) : in1;
            xp_next = P[(size_t)tokens[tok_base + tn] * NC + cb + g];
        }

        // rec[g] = b_r[g] + sum_k h[k] * U[k][g]  (4 accs break dep chain)
        float a0 = brec, a1 = 0.f, a2 = 0.f, a3 = 0.f;
        const float4* h4 = (const float4*)hcur;
        #pragma unroll
        for (int k4 = 0; k4 < HH / 4; ++k4) {
            float4 hv = h4[k4];
            a0 += hv.x * u[k4 * 4 + 0];
            a1 += hv.y * u[k4 * 4 + 1];
            a2 += hv.z * u[k4 * 4 + 2];
            a3 += hv.w * u[k4 * 4 + 3];
        }
        const float rec = (a0 + a1) + (a2 + a3);

        float my_sz = 0.f;
        if (g < HH)            my_sz = rec + xp;          // z-gate pre-act
        else if (g < 2 * HH)   sr[g - HH] = rec + xp;     // r-gate pre-act
        else { rh_s[g - 2*HH] = rec; xh_s[g - 2*HH] = xp; }
        BAR();                                            // barrier1

        if (g < HH) {
            float z = __builtin_amdgcn_rcpf(1.f + __expf(-my_sz));
            float r = __builtin_amdgcn_rcpf(1.f + __expf(-sr[g]));
            float ph = xh_s[g] + r * rh_s[g];
            ph = fminf(fmaxf(ph, -15.f), 15.f);
            float e  = __expf(-2.f * ph);
            float hh = (1.f - e) * __builtin_amdgcn_rcpf(1.f + e);  // tanh
            float hn = z * hreg + (1.f - z) * hh;
            hreg = hn;
            hcur[g] = hn;
            out[((size_t)b * TT + tcur) * 256 + d * HH + g] = hn;
        }
        BAR();                                            // barrier2
    }

    if (g < HH) {
        // final states: [B*T*256 | h_f (B*H) | h_b (B*H)]
        out[(size_t)BB * TT * 256 + (size_t)d * BB * HH + b * HH + g] = hreg;
    }
}

// ---------------------------------------------------------------------------
extern "C" void kernel_launch(void* const* d_in, const int* in_sizes, int n_in,
                              void* d_out, int out_size, void* d_ws, size_t ws_size,
                              hipStream_t stream)
{
    const int*   tokens  = (const int*)  d_in[0];
    const float* state_f = (const float*)d_in[1];
    const float* state_b = (const float*)d_in[2];
    const float* emb     = (const float*)d_in[3];
    const float* W_f     = (const float*)d_in[4];
    const float* U_f     = (const float*)d_in[5];
    const float* b_f     = (const float*)d_in[6];
    const float* W_b     = (const float*)d_in[7];
    const float* U_b     = (const float*)d_in[8];
    const float* b_b     = (const float*)d_in[9];
    float*       out     = (float*)d_out;

    float* P = (float*)d_ws;   // needs 32000*768*4 = 98.3 MB of workspace

    dim3 gp(VV / 128, NC / 128);           // 250 x 6
    proj_kernel<<<gp, 256, 0, stream>>>(emb, W_f, W_b, b_f, b_b, P);

    dim3 gs(BB, 2);                         // 128 batch x 2 directions
    scan_kernel<<<gs, 384, 0, stream>>>(tokens, state_f, state_b,
                                        U_f, U_b, b_f, b_b, P, out);
}

// Round 5
// 667.503 us; speedup vs baseline: 1.1955x; 1.0731x over previous
//
#include <hip/hip_runtime.h>
#include <stddef.h>

// Sizes (fixed by the problem)
#define BB   128      // batch
#define TT   512      // time
#define VV   32000    // vocab
#define DD   300      // emb dim
#define HH   128      // hidden
#define G3   384      // 3*H
#define NC   768      // 2*3*H (fwd+bwd projected gates)

// ---------------------------------------------------------------------------
// Kernel 1: P[v][g] = emb[v][:] @ Wcat[:, g] + b_i[g]   (unchanged, ~231 us)
// ---------------------------------------------------------------------------
__global__ __launch_bounds__(256) void proj_kernel(
    const float* __restrict__ emb,
    const float* __restrict__ Wf, const float* __restrict__ Wb,
    const float* __restrict__ bf, const float* __restrict__ bb,
    float* __restrict__ P)
{
    __shared__ float As[12 * 128];       // [k][row]
    __shared__ float Bs[12 * 140];       // [k][skewed col], stride 140

    const int m0 = blockIdx.x * 128;     // vocab-row tile
    const int n0 = blockIdx.y * 128;     // output-col tile

    const float* Wsrc;
    const float* bsrc;
    int cb;
    if (n0 < G3) { Wsrc = Wf; bsrc = bf; cb = n0; }
    else         { Wsrc = Wb; bsrc = bb; cb = n0 - G3; }

    const int t  = threadIdx.x;
    const int tx = t & 15;               // col group (8 cols each)
    const int ty = t >> 4;               // row group (8 rows each)

    float acc[8][8];
    #pragma unroll
    for (int i = 0; i < 8; ++i)
        #pragma unroll
        for (int j = 0; j < 8; ++j) acc[i][j] = 0.f;

    const int bread = tx * 8 + ((tx >> 2) << 2);

    for (int kt = 0; kt < 25; ++kt) {
        const int kbase = kt * 12;

        {
            int row = t & 127, ch = t >> 7;               // ch 0..1 covers k 0..7
            float4 v = *(const float4*)(emb + (size_t)(m0 + row) * DD + kbase + ch * 4);
            As[(ch * 4 + 0) * 128 + row] = v.x;
            As[(ch * 4 + 1) * 128 + row] = v.y;
            As[(ch * 4 + 2) * 128 + row] = v.z;
            As[(ch * 4 + 3) * 128 + row] = v.w;
            if (t < 128) {                                // k 8..11 for all rows
                int row2 = t;
                float4 v2 = *(const float4*)(emb + (size_t)(m0 + row2) * DD + kbase + 8);
                As[ 8 * 128 + row2] = v2.x;
                As[ 9 * 128 + row2] = v2.y;
                As[10 * 128 + row2] = v2.z;
                As[11 * 128 + row2] = v2.w;
            }
        }
        {
            int kr = t >> 5, cg = t & 31, col = cg * 4;
            float4 w = *(const float4*)(Wsrc + (size_t)(kbase + kr) * G3 + cb + col);
            int sc = col + ((col >> 5) << 2);
            *(float4*)&Bs[kr * 140 + sc] = w;
            if (t < 128) {                                // k rows 8..11
                int kr2 = 8 + (t >> 5), cg2 = t & 31, col2 = cg2 * 4;
                float4 w2 = *(const float4*)(Wsrc + (size_t)(kbase + kr2) * G3 + cb + col2);
                int sc2 = col2 + ((col2 >> 5) << 2);
                *(float4*)&Bs[kr2 * 140 + sc2] = w2;
            }
        }
        __syncthreads();

        #pragma unroll
        for (int kk = 0; kk < 12; ++kk) {
            const float4* ap = (const float4*)&As[kk * 128 + ty * 8];
            const float4* bp = (const float4*)&Bs[kk * 140 + bread];
            float4 a0 = ap[0], a1 = ap[1];
            float4 b0 = bp[0], b1 = bp[1];
            float a[8]   = {a0.x,a0.y,a0.z,a0.w,a1.x,a1.y,a1.z,a1.w};
            float bfr[8] = {b0.x,b0.y,b0.z,b0.w,b1.x,b1.y,b1.z,b1.w};
            #pragma unroll
            for (int i = 0; i < 8; ++i)
                #pragma unroll
                for (int j = 0; j < 8; ++j)
                    acc[i][j] += a[i] * bfr[j];
        }
        __syncthreads();
    }

    float bias[8];
    #pragma unroll
    for (int j = 0; j < 8; ++j) bias[j] = bsrc[cb + tx * 8 + j];

    #pragma unroll
    for (int i = 0; i < 8; ++i) {
        int row = m0 + ty * 8 + i;
        float4 o0 = { acc[i][0] + bias[0], acc[i][1] + bias[1],
                      acc[i][2] + bias[2], acc[i][3] + bias[3] };
        float4 o1 = { acc[i][4] + bias[4], acc[i][5] + bias[5],
                      acc[i][6] + bias[6], acc[i][7] + bias[7] };
        float* dst = P + (size_t)row * NC + n0 + tx * 8;
        *(float4*)dst       = o0;
        *(float4*)(dst + 4) = o1;
    }
}

// ---------------------------------------------------------------------------
// DPP quad-butterfly add: x += lane(x ^ m) within each quad. Pure VALU
// (v_mov_b32_dpp + v_add), no DS traffic.
// quad_perm[1,0,3,2] = 0xB1 (xor 1), quad_perm[2,3,0,1] = 0x4E (xor 2).
// ---------------------------------------------------------------------------
template<int CTRL>
__device__ __forceinline__ float qp_add(float x) {
    union { float f; int i; } a, r;
    a.f = x;
    r.i = __builtin_amdgcn_update_dpp(0, a.i, CTRL, 0xF, 0xF, true);
    return x + r.f;
}

// ---------------------------------------------------------------------------
// Kernel 2: GRU scan, Config C.
// grid (128 batch, 2 dirs) x 384 threads, 1 block/CU.
// Round-4 evidence: step time 2265 cy == 6 waves x 32 ds_read_b128 x 12 cy —
// the h-broadcast (every lane reads all 128 h) saturates the LDS pipe.
// Fix: thread t owns 4 columns {4q..4q+3} (q=t>>2) over K-slice s=t&3 of 32
// -> per-lane h-read is 8 x b128 (4x less LDS), 128 FMAs reuse each h 4x.
// Partial sums reduced across the quad with DPP (no DS), lane t ends with
// the full rec for column t. h stored skewed (word 36*(g>>5)+(g&31)) so the
// four slice bases hit disjoint bank quartets -> conflict-free broadcast.
// ---------------------------------------------------------------------------
#define BAR() asm volatile("s_waitcnt lgkmcnt(0)\n\ts_barrier" ::: "memory")

__global__ __launch_bounds__(384) void scan_kernel(
    const int*   __restrict__ tokens,
    const float* __restrict__ state_f, const float* __restrict__ state_b,
    const float* __restrict__ Uf, const float* __restrict__ Ub,
    const float* __restrict__ bf, const float* __restrict__ bb,
    const float* __restrict__ P,
    float* __restrict__ out)
{
    const int b = blockIdx.x;
    const int d = blockIdx.y;            // 0 = fwd, 1 = bwd
    const int t = threadIdx.x;           // 0..383 == output column
    const int s = t & 3;                 // K-slice (k in [32s, 32s+32))
    const int q = t >> 2;                // column group (cols 4q..4q+3)

    const float* U  = d ? Ub : Uf;
    const float* bv = d ? bb : bf;
    const float* st = d ? state_b : state_f;
    const int    cb = d ? G3 : 0;        // column base into P

    __shared__ __align__(16) float hs[144];   // skewed h: word 36*(k>>5)+(k&31)
    __shared__ float recs[G3];
    __shared__ float xhs[HH];

    // u4[k].{x,y,z,w} = U[32s+k][4q + {0,1,2,3}]  (float4-coalesced)
    float4 u4[32];
    #pragma unroll
    for (int k = 0; k < 32; ++k)
        u4[k] = *(const float4*)(U + (size_t)(s * 32 + k) * G3 + (q << 2));

    const float brec = bv[G3 + t];       // recurrent bias b[1][col]

    float hreg = 0.f;
    if (t < HH) { hreg = st[b * HH + t]; hs[36 * (t >> 5) + (t & 31)] = hreg; }
    __syncthreads();

    const int tok_base = b * TT;
    int tfirst = d ? (TT - 1) : 0;
    float xp_next = P[(size_t)tokens[tok_base + tfirst] * NC + cb + t];

    for (int i = 0; i < TT; ++i) {
        const int tcur = d ? (TT - 1 - i) : i;
        const float xp = xp_next;
        {   // branchless prefetch (last iter re-reads same row; harmless)
            int in1 = (i + 1 < TT) ? (i + 1) : i;
            int tn  = d ? (TT - 1 - in1) : in1;
            xp_next = P[(size_t)tokens[tok_base + tn] * NC + cb + t];
        }

        // partials for 4 columns over this lane's 32-k slice
        const float4* hp = (const float4*)&hs[36 * s];
        float acc0 = 0.f, acc1 = 0.f, acc2 = 0.f, acc3 = 0.f;
        #pragma unroll
        for (int k4 = 0; k4 < 8; ++k4) {
            float4 hv = hp[k4];
            acc0 += hv.x * u4[k4 * 4 + 0].x;
            acc1 += hv.x * u4[k4 * 4 + 0].y;
            acc2 += hv.x * u4[k4 * 4 + 0].z;
            acc3 += hv.x * u4[k4 * 4 + 0].w;
            acc0 += hv.y * u4[k4 * 4 + 1].x;
            acc1 += hv.y * u4[k4 * 4 + 1].y;
            acc2 += hv.y * u4[k4 * 4 + 1].z;
            acc3 += hv.y * u4[k4 * 4 + 1].w;
            acc0 += hv.z * u4[k4 * 4 + 2].x;
            acc1 += hv.z * u4[k4 * 4 + 2].y;
            acc2 += hv.z * u4[k4 * 4 + 2].z;
            acc3 += hv.z * u4[k4 * 4 + 2].w;
            acc0 += hv.w * u4[k4 * 4 + 3].x;
            acc1 += hv.w * u4[k4 * 4 + 3].y;
            acc2 += hv.w * u4[k4 * 4 + 3].z;
            acc3 += hv.w * u4[k4 * 4 + 3].w;
        }

        // quad butterfly: every lane in the quad ends with all 4 full sums
        acc0 = qp_add<0xB1>(acc0); acc0 = qp_add<0x4E>(acc0);
        acc1 = qp_add<0xB1>(acc1); acc1 = qp_add<0x4E>(acc1);
        acc2 = qp_add<0xB1>(acc2); acc2 = qp_add<0x4E>(acc2);
        acc3 = qp_add<0xB1>(acc3); acc3 = qp_add<0x4E>(acc3);

        // lane t keeps column t = 4q + s  (static select, no dyn reg index)
        float rec = (s == 0) ? acc0 : (s == 1) ? acc1 : (s == 2) ? acc2 : acc3;
        rec += brec;

        float my_sz = 0.f;
        if (t < HH)            my_sz = rec + xp;          // z pre-act (local)
        else if (t < 2 * HH)   recs[t] = rec + xp;        // r pre-act
        else { recs[t] = rec; xhs[t - 2 * HH] = xp; }     // rh | xh
        BAR();                                            // barrier1

        if (t < HH) {
            float z = __builtin_amdgcn_rcpf(1.f + __expf(-my_sz));
            float r = __builtin_amdgcn_rcpf(1.f + __expf(-recs[HH + t]));
            float ph = xhs[t] + r * recs[2 * HH + t];
            ph = fminf(fmaxf(ph, -15.f), 15.f);
            float e  = __expf(-2.f * ph);
            float hh = (1.f - e) * __builtin_amdgcn_rcpf(1.f + e);  // tanh
            float hn = z * hreg + (1.f - z) * hh;
            hreg = hn;
            hs[36 * (t >> 5) + (t & 31)] = hn;
            out[((size_t)b * TT + tcur) * 256 + d * HH + t] = hn;
        }
        BAR();                                            // barrier2
    }

    if (t < HH) {
        // final states: [B*T*256 | h_f (B*H) | h_b (B*H)]
        out[(size_t)BB * TT * 256 + (size_t)d * BB * HH + b * HH + t] = hreg;
    }
}

// ---------------------------------------------------------------------------
extern "C" void kernel_launch(void* const* d_in, const int* in_sizes, int n_in,
                              void* d_out, int out_size, void* d_ws, size_t ws_size,
                              hipStream_t stream)
{
    const int*   tokens  = (const int*)  d_in[0];
    const float* state_f = (const float*)d_in[1];
    const float* state_b = (const float*)d_in[2];
    const float* emb     = (const float*)d_in[3];
    const float* W_f     = (const float*)d_in[4];
    const float* U_f     = (const float*)d_in[5];
    const float* b_f     = (const float*)d_in[6];
    const float* W_b     = (const float*)d_in[7];
    const float* U_b     = (const float*)d_in[8];
    const float* b_b     = (const float*)d_in[9];
    float*       out     = (float*)d_out;

    float* P = (float*)d_ws;   // needs 32000*768*4 = 98.3 MB of workspace

    dim3 gp(VV / 128, NC / 128);           // 250 x 6
    proj_kernel<<<gp, 256, 0, stream>>>(emb, W_f, W_b, b_f, b_b, P);

    dim3 gs(BB, 2);                         // 128 batch x 2 directions
    scan_kernel<<<gs, 384, 0, stream>>>(tokens, state_f, state_b,
                                        U_f, U_b, b_f, b_b, P, out);
}

// Round 6
// 581.206 us; speedup vs baseline: 1.3730x; 1.1485x over previous
//
#include <hip/hip_runtime.h>
#include <stddef.h>

// Sizes (fixed by the problem)
#define BB   128      // batch
#define TT   512      // time
#define VV   32000    // vocab
#define DD   300      // emb dim
#define HH   128      // hidden
#define G3   384      // 3*H
#define NC   768      // 2*3*H (fwd+bwd projected gates)

// ---------------------------------------------------------------------------
// Kernel 1: P[v][g] = emb[v][:] @ Wcat[:, g] + b_i[g]   (unchanged, ~231 us)
// ---------------------------------------------------------------------------
__global__ __launch_bounds__(256) void proj_kernel(
    const float* __restrict__ emb,
    const float* __restrict__ Wf, const float* __restrict__ Wb,
    const float* __restrict__ bf, const float* __restrict__ bb,
    float* __restrict__ P)
{
    __shared__ float As[12 * 128];       // [k][row]
    __shared__ float Bs[12 * 140];       // [k][skewed col], stride 140

    const int m0 = blockIdx.x * 128;     // vocab-row tile
    const int n0 = blockIdx.y * 128;     // output-col tile

    const float* Wsrc;
    const float* bsrc;
    int cb;
    if (n0 < G3) { Wsrc = Wf; bsrc = bf; cb = n0; }
    else         { Wsrc = Wb; bsrc = bb; cb = n0 - G3; }

    const int t  = threadIdx.x;
    const int tx = t & 15;               // col group (8 cols each)
    const int ty = t >> 4;               // row group (8 rows each)

    float acc[8][8];
    #pragma unroll
    for (int i = 0; i < 8; ++i)
        #pragma unroll
        for (int j = 0; j < 8; ++j) acc[i][j] = 0.f;

    const int bread = tx * 8 + ((tx >> 2) << 2);

    for (int kt = 0; kt < 25; ++kt) {
        const int kbase = kt * 12;

        {
            int row = t & 127, ch = t >> 7;               // ch 0..1 covers k 0..7
            float4 v = *(const float4*)(emb + (size_t)(m0 + row) * DD + kbase + ch * 4);
            As[(ch * 4 + 0) * 128 + row] = v.x;
            As[(ch * 4 + 1) * 128 + row] = v.y;
            As[(ch * 4 + 2) * 128 + row] = v.z;
            As[(ch * 4 + 3) * 128 + row] = v.w;
            if (t < 128) {                                // k 8..11 for all rows
                int row2 = t;
                float4 v2 = *(const float4*)(emb + (size_t)(m0 + row2) * DD + kbase + 8);
                As[ 8 * 128 + row2] = v2.x;
                As[ 9 * 128 + row2] = v2.y;
                As[10 * 128 + row2] = v2.z;
                As[11 * 128 + row2] = v2.w;
            }
        }
        {
            int kr = t >> 5, cg = t & 31, col = cg * 4;
            float4 w = *(const float4*)(Wsrc + (size_t)(kbase + kr) * G3 + cb + col);
            int sc = col + ((col >> 5) << 2);
            *(float4*)&Bs[kr * 140 + sc] = w;
            if (t < 128) {                                // k rows 8..11
                int kr2 = 8 + (t >> 5), cg2 = t & 31, col2 = cg2 * 4;
                float4 w2 = *(const float4*)(Wsrc + (size_t)(kbase + kr2) * G3 + cb + col2);
                int sc2 = col2 + ((col2 >> 5) << 2);
                *(float4*)&Bs[kr2 * 140 + sc2] = w2;
            }
        }
        __syncthreads();

        #pragma unroll
        for (int kk = 0; kk < 12; ++kk) {
            const float4* ap = (const float4*)&As[kk * 128 + ty * 8];
            const float4* bp = (const float4*)&Bs[kk * 140 + bread];
            float4 a0 = ap[0], a1 = ap[1];
            float4 b0 = bp[0], b1 = bp[1];
            float a[8]   = {a0.x,a0.y,a0.z,a0.w,a1.x,a1.y,a1.z,a1.w};
            float bfr[8] = {b0.x,b0.y,b0.z,b0.w,b1.x,b1.y,b1.z,b1.w};
            #pragma unroll
            for (int i = 0; i < 8; ++i)
                #pragma unroll
                for (int j = 0; j < 8; ++j)
                    acc[i][j] += a[i] * bfr[j];
        }
        __syncthreads();
    }

    float bias[8];
    #pragma unroll
    for (int j = 0; j < 8; ++j) bias[j] = bsrc[cb + tx * 8 + j];

    #pragma unroll
    for (int i = 0; i < 8; ++i) {
        int row = m0 + ty * 8 + i;
        float4 o0 = { acc[i][0] + bias[0], acc[i][1] + bias[1],
                      acc[i][2] + bias[2], acc[i][3] + bias[3] };
        float4 o1 = { acc[i][4] + bias[4], acc[i][5] + bias[5],
                      acc[i][6] + bias[6], acc[i][7] + bias[7] };
        float* dst = P + (size_t)row * NC + n0 + tx * 8;
        *(float4*)dst       = o0;
        *(float4*)(dst + 4) = o1;
    }
}

// ---------------------------------------------------------------------------
// DPP quad-butterfly add: x += lane(x ^ m) within each quad. Pure VALU.
// quad_perm[1,0,3,2] = 0xB1 (xor 1), quad_perm[2,3,0,1] = 0x4E (xor 2).
// ---------------------------------------------------------------------------
template<int CTRL>
__device__ __forceinline__ float qp_add(float x) {
    union { float f; int i; } a, r;
    a.f = x;
    r.i = __builtin_amdgcn_update_dpp(0, a.i, CTRL, 0xF, 0xF, true);
    return x + r.f;
}

// ---------------------------------------------------------------------------
// Kernel 2: GRU scan, gate-local config.
// grid (128 batch, 2 dirs) x 512 threads (8 waves, 2/SIMD), 1 block/CU.
// Lane t = (q, s): q = t>>2 in [0,128) owns ALL THREE gate columns of h-col
// q (U cols q, q+128, q+256); s = t&3 owns K-slice [32s, 32s+32).
// Quad-DPP butterfly gives every lane the full rec_z/rec_r/rec_hh for col q
// -> no LDS gate exchange, gate math on all 512 lanes (redundant x4),
// s==0 lane writes h and out. h double-buffered in LDS (race-free with a
// single lgkm barrier per step). Tokens staged in LDS (kills the per-step
// global token->prefetch serial chain).
// Round-5 evidence: u[128] gets AGPR'd (VGPR_Count 84, VALU 2x theory);
// u is now 96 floats and even with the AGPR tax VALU (~850cy) stays under
// the 768cy LDS h-broadcast floor -> design robust to the allocator.
// ---------------------------------------------------------------------------
#define BAR() asm volatile("s_waitcnt lgkmcnt(0)\n\ts_barrier" ::: "memory")

__global__ __launch_bounds__(512, 2) void scan_kernel(
    const int*   __restrict__ tokens,
    const float* __restrict__ state_f, const float* __restrict__ state_b,
    const float* __restrict__ Uf, const float* __restrict__ Ub,
    const float* __restrict__ bf, const float* __restrict__ bb,
    const float* __restrict__ P,
    float* __restrict__ out)
{
    const int b = blockIdx.x;
    const int d = blockIdx.y;            // 0 = fwd, 1 = bwd
    const int t = threadIdx.x;           // 0..511
    const int s = t & 3;                 // K-slice
    const int q = t >> 2;                // h column 0..127

    const float* U  = d ? Ub : Uf;
    const float* bv = d ? bb : bf;
    const float* st = d ? state_b : state_f;
    const int    cb = d ? G3 : 0;        // column base into P

    __shared__ __align__(16) float hs[2][144];  // skewed: word 36*(k>>5)+(k&31)
    __shared__ int tok_s[TT];

    tok_s[t] = tokens[b * TT + t];       // 512 threads == TT

    // U columns for the three gates of col q, K-slice rows 32s..32s+31
    float uz[32], ur[32], uh[32];
    #pragma unroll
    for (int k = 0; k < 32; ++k) {
        const float* Urow = U + (size_t)(s * 32 + k) * G3;
        uz[k] = Urow[q];
        ur[k] = Urow[HH + q];
        uh[k] = Urow[2 * HH + q];
    }
    const float bz = bv[G3 + q];
    const float br = bv[G3 + HH + q];
    const float bh = bv[G3 + 2 * HH + q];

    float hreg = st[b * HH + q];         // redundant across the quad
    if (t < HH) hs[0][36 * (t >> 5) + (t & 31)] = st[b * HH + t];
    __syncthreads();

    // prefetch step-0 xp triple
    float xz_n, xr_n, xh_n;
    {
        int tok = tok_s[d ? (TT - 1) : 0];
        const float* pr = P + (size_t)tok * NC + cb;
        xz_n = pr[q]; xr_n = pr[HH + q]; xh_n = pr[2 * HH + q];
    }

    int cur = 0;
    for (int i = 0; i < TT; ++i) {
        const int tcur = d ? (TT - 1 - i) : i;
        const float xz = xz_n, xr = xr_n, xh = xh_n;
        {   // prefetch next step (last iter re-reads same row; harmless)
            int in1 = (i + 1 < TT) ? (i + 1) : i;
            int tok = tok_s[d ? (TT - 1 - in1) : in1];
            const float* pr = P + (size_t)tok * NC + cb;
            xz_n = pr[q]; xr_n = pr[HH + q]; xh_n = pr[2 * HH + q];
        }

        // three dot-product partials over this lane's 32-k h slice
        const float4* hp = (const float4*)&hs[cur][36 * s];
        float az = 0.f, ar = 0.f, ah = 0.f;
        #pragma unroll
        for (int k4 = 0; k4 < 8; ++k4) {
            float4 hv = hp[k4];
            az += hv.x * uz[4*k4+0]; ar += hv.x * ur[4*k4+0]; ah += hv.x * uh[4*k4+0];
            az += hv.y * uz[4*k4+1]; ar += hv.y * ur[4*k4+1]; ah += hv.y * uh[4*k4+1];
            az += hv.z * uz[4*k4+2]; ar += hv.z * ur[4*k4+2]; ah += hv.z * uh[4*k4+2];
            az += hv.w * uz[4*k4+3]; ar += hv.w * ur[4*k4+3]; ah += hv.w * uh[4*k4+3];
        }
        // quad butterfly: all 4 lanes end with the full sums for col q
        az = qp_add<0xB1>(az); az = qp_add<0x4E>(az);
        ar = qp_add<0xB1>(ar); ar = qp_add<0x4E>(ar);
        ah = qp_add<0xB1>(ah); ah = qp_add<0x4E>(ah);

        // gates (redundant across quad — cheaper than an LDS exchange)
        float z = __builtin_amdgcn_rcpf(1.f + __expf(-(az + bz + xz)));
        float r = __builtin_amdgcn_rcpf(1.f + __expf(-(ar + br + xr)));
        float ph = xh + r * (ah + bh);
        ph = fminf(fmaxf(ph, -15.f), 15.f);
        float e  = __expf(-2.f * ph);
        float hh = (1.f - e) * __builtin_amdgcn_rcpf(1.f + e);      // tanh
        float hn = z * hreg + (1.f - z) * hh;
        hreg = hn;

        const int nxt = cur ^ 1;
        if (s == 0) {
            hs[nxt][36 * (q >> 5) + (q & 31)] = hn;
            out[((size_t)b * TT + tcur) * 256 + d * HH + q] = hn;
        }
        BAR();           // writes to hs[nxt] visible; reads of hs[cur] done
        cur = nxt;
    }

    if (s == 0) {
        // final states: [B*T*256 | h_f (B*H) | h_b (B*H)]
        out[(size_t)BB * TT * 256 + (size_t)d * BB * HH + b * HH + q] = hreg;
    }
}

// ---------------------------------------------------------------------------
extern "C" void kernel_launch(void* const* d_in, const int* in_sizes, int n_in,
                              void* d_out, int out_size, void* d_ws, size_t ws_size,
                              hipStream_t stream)
{
    const int*   tokens  = (const int*)  d_in[0];
    const float* state_f = (const float*)d_in[1];
    const float* state_b = (const float*)d_in[2];
    const float* emb     = (const float*)d_in[3];
    const float* W_f     = (const float*)d_in[4];
    const float* U_f     = (const float*)d_in[5];
    const float* b_f     = (const float*)d_in[6];
    const float* W_b     = (const float*)d_in[7];
    const float* U_b     = (const float*)d_in[8];
    const float* b_b     = (const float*)d_in[9];
    float*       out     = (float*)d_out;

    float* P = (float*)d_ws;   // needs 32000*768*4 = 98.3 MB of workspace

    dim3 gp(VV / 128, NC / 128);           // 250 x 6
    proj_kernel<<<gp, 256, 0, stream>>>(emb, W_f, W_b, b_f, b_b, P);

    dim3 gs(BB, 2);                         // 128 batch x 2 directions
    scan_kernel<<<gs, 512, 0, stream>>>(tokens, state_f, state_b,
                                        U_f, U_b, b_f, b_b, P, out);
}

// Round 8
// 500.478 us; speedup vs baseline: 1.5944x; 1.1613x over previous
//
#include <hip/hip_runtime.h>
#include <stddef.h>

// Sizes (fixed by the problem)
#define BB   128      // batch
#define TT   512      // time
#define VV   32000    // vocab
#define DD   300      // emb dim
#define HH   128      // hidden
#define G3   384      // 3*H
#define NC   768      // 2*3*H (fwd+bwd projected gates)

// __builtin_amdgcn_cvt_pkrtz returns __fp16 ext_vector(2); use that element
// type throughout (Round-7 compile failure was _Float16 vs __fp16 mismatch).
typedef __fp16 half_t;
typedef __fp16 half2_t __attribute__((ext_vector_type(2)));

// ---------------------------------------------------------------------------
// Kernel 1: P[v][g] = emb[v][:] @ Wcat[:, g] + b_i[g]
// f16-pair variant: tiles staged as packed f16 (pairs along K), inner loop
// uses v_dot2_f32_f16 (full-rate, 2 FLOP-pairs/slot) -> VALU and LDS halved
// vs the fp32 version. Accumulation stays fp32. Both tiles skewed
// (+4 half2 per 32) to kill the 4-way ty/tx bank aliasing.
// ---------------------------------------------------------------------------
#define PSTR 140
__global__ __launch_bounds__(256) void proj_kernel(
    const float* __restrict__ emb,
    const float* __restrict__ Wf, const float* __restrict__ Wb,
    const float* __restrict__ bf, const float* __restrict__ bb,
    float* __restrict__ P)
{
    __shared__ __align__(16) half2_t As2[6][PSTR];   // [k2][skewed row]
    __shared__ __align__(16) half2_t Bs2[6][PSTR];   // [k2][skewed col]

    const int m0 = blockIdx.x * 128;     // vocab-row tile
    const int n0 = blockIdx.y * 128;     // output-col tile

    const float* Wsrc;
    const float* bsrc;
    int cb;
    if (n0 < G3) { Wsrc = Wf; bsrc = bf; cb = n0; }
    else         { Wsrc = Wb; bsrc = bb; cb = n0 - G3; }

    const int t  = threadIdx.x;
    const int tx = t & 15;               // col group (8 cols each)
    const int ty = t >> 4;               // row group (8 rows each)

    float acc[8][8];
    #pragma unroll
    for (int i = 0; i < 8; ++i)
        #pragma unroll
        for (int j = 0; j < 8; ++j) acc[i][j] = 0.f;

    // skewed read bases: idx' = idx + (idx>>5)*4  (idx = 8*group)
    const int aread = ty * 8 + ((ty >> 2) << 2);
    const int bread = tx * 8 + ((tx >> 2) << 2);

    for (int kt = 0; kt < 25; ++kt) {
        const int kbase = kt * 12;

        // ---- stage A (128 rows x 12 k) -> As2[k2][srow], pairs along k ----
        {
            int row = t & 127, ch = t >> 7;           // ch 0..1 -> k 0..7
            int srow = row + ((row >> 5) << 2);
            float4 v = *(const float4*)(emb + (size_t)(m0 + row) * DD + kbase + ch * 4);
            As2[ch * 2 + 0][srow] = __builtin_amdgcn_cvt_pkrtz(v.x, v.y);
            As2[ch * 2 + 1][srow] = __builtin_amdgcn_cvt_pkrtz(v.z, v.w);
            if (t < 128) {                            // k 8..11
                int row2 = t, srow2 = row2 + ((row2 >> 5) << 2);
                float4 v2 = *(const float4*)(emb + (size_t)(m0 + row2) * DD + kbase + 8);
                As2[4][srow2] = __builtin_amdgcn_cvt_pkrtz(v2.x, v2.y);
                As2[5][srow2] = __builtin_amdgcn_cvt_pkrtz(v2.z, v2.w);
            }
        }
        // ---- stage B (12 k x 128 cols) -> Bs2[k2][scol], pairs along k ----
        if (t < 192) {
            int k2 = t >> 5, col = (t & 31) * 4;
            int r0 = kbase + 2 * k2;
            float4 w0 = *(const float4*)(Wsrc + (size_t)r0 * G3 + cb + col);
            float4 w1 = *(const float4*)(Wsrc + (size_t)(r0 + 1) * G3 + cb + col);
            int sc = col + ((col >> 5) << 2);
            half2_t pk[4];
            pk[0] = __builtin_amdgcn_cvt_pkrtz(w0.x, w1.x);
            pk[1] = __builtin_amdgcn_cvt_pkrtz(w0.y, w1.y);
            pk[2] = __builtin_amdgcn_cvt_pkrtz(w0.z, w1.z);
            pk[3] = __builtin_amdgcn_cvt_pkrtz(w0.w, w1.w);
            *(float4*)&Bs2[k2][sc] = *(float4*)&pk[0];
        }
        __syncthreads();

        #pragma unroll
        for (int kk = 0; kk < 6; ++kk) {
            const half2_t* ap = &As2[kk][aread];
            const half2_t* bp = &Bs2[kk][bread];
            half2_t a2[8], b2[8];
            *(float4*)&a2[0] = *(const float4*)&ap[0];
            *(float4*)&a2[4] = *(const float4*)&ap[4];
            *(float4*)&b2[0] = *(const float4*)&bp[0];
            *(float4*)&b2[4] = *(const float4*)&bp[4];
            #pragma unroll
            for (int i = 0; i < 8; ++i)
                #pragma unroll
                for (int j = 0; j < 8; ++j)
                    acc[i][j] = __builtin_amdgcn_fdot2(a2[i], b2[j], acc[i][j], false);
        }
        __syncthreads();
    }

    // ---- epilogue: + input bias (fp32), store fp32 ----
    float bias[8];
    #pragma unroll
    for (int j = 0; j < 8; ++j) bias[j] = bsrc[cb + tx * 8 + j];

    #pragma unroll
    for (int i = 0; i < 8; ++i) {
        int row = m0 + ty * 8 + i;
        float4 o0 = { acc[i][0] + bias[0], acc[i][1] + bias[1],
                      acc[i][2] + bias[2], acc[i][3] + bias[3] };
        float4 o1 = { acc[i][4] + bias[4], acc[i][5] + bias[5],
                      acc[i][6] + bias[6], acc[i][7] + bias[7] };
        float* dst = P + (size_t)row * NC + n0 + tx * 8;
        *(float4*)dst       = o0;
        *(float4*)(dst + 4) = o1;
    }
}

// ---------------------------------------------------------------------------
// DPP quad-butterfly add (pure VALU, no DS).
// quad_perm[1,0,3,2] = 0xB1 (xor 1), quad_perm[2,3,0,1] = 0x4E (xor 2).
// ---------------------------------------------------------------------------
template<int CTRL>
__device__ __forceinline__ float qp_add(float x) {
    union { float f; int i; } a, r;
    a.f = x;
    r.i = __builtin_amdgcn_update_dpp(0, a.i, CTRL, 0xF, 0xF, true);
    return x + r.f;
}

// ---------------------------------------------------------------------------
// Kernel 2: GRU scan, gate-local + f16 dot config.
// grid (128 batch, 2 dirs) x 512 threads (8 waves, 2/SIMD), 1 block/CU.
// Lane t=(q,s): q=t>>2 owns all three gate columns of h-col q; s=t&3 owns
// K-slice [32s,32s+32). h broadcast via LDS in f16 (owner's hreg stays
// fp32; only other-column reads are f16-rounded). U preloaded as packed
// f16 pairs (48 regs). Recurrent matvec = 48 v_dot2_f32_f16 per lane
// (full-rate, halves Round-6's 96 fmac + the 96-reg pressure).
// Quad-DPP butterfly -> all 4 lanes own the col's full sums -> gate math
// redundant on quad, no LDS gate exchange, ONE lgkm-only barrier per step.
// ---------------------------------------------------------------------------
#define BAR() asm volatile("s_waitcnt lgkmcnt(0)\n\ts_barrier" ::: "memory")

__global__ __launch_bounds__(512) void scan_kernel(
    const int*   __restrict__ tokens,
    const float* __restrict__ state_f, const float* __restrict__ state_b,
    const float* __restrict__ Uf, const float* __restrict__ Ub,
    const float* __restrict__ bf, const float* __restrict__ bb,
    const float* __restrict__ P,
    float* __restrict__ out)
{
    const int b = blockIdx.x;
    const int d = blockIdx.y;            // 0 = fwd, 1 = bwd
    const int t = threadIdx.x;           // 0..511
    const int s = t & 3;                 // K-slice
    const int q = t >> 2;                // h column 0..127

    const float* U  = d ? Ub : Uf;
    const float* bv = d ? bb : bf;
    const float* st = d ? state_b : state_f;
    const int    cb = d ? G3 : 0;        // column base into P

    __shared__ __align__(16) half_t hs[2][HH];   // f16 h, double-buffered
    __shared__ int tok_s[TT];

    tok_s[t] = tokens[b * TT + t];       // 512 threads == TT

    // U columns for the three gates of col q, packed f16 pairs along k
    half2_t uz2[16], ur2[16], uh2[16];
    #pragma unroll
    for (int k2 = 0; k2 < 16; ++k2) {
        const float* U0 = U + (size_t)(s * 32 + 2 * k2) * G3;
        const float* U1 = U0 + G3;
        uz2[k2] = __builtin_amdgcn_cvt_pkrtz(U0[q],          U1[q]);
        ur2[k2] = __builtin_amdgcn_cvt_pkrtz(U0[HH + q],     U1[HH + q]);
        uh2[k2] = __builtin_amdgcn_cvt_pkrtz(U0[2 * HH + q], U1[2 * HH + q]);
    }
    const float bz = bv[G3 + q];
    const float br = bv[G3 + HH + q];
    const float bh = bv[G3 + 2 * HH + q];

    float hreg = st[b * HH + q];         // fp32, redundant across the quad
    if (t < HH) hs[0][t] = (half_t)st[b * HH + t];
    __syncthreads();

    // prefetch step-0 xp triple (fp32)
    float xz_n, xr_n, xh_n;
    {
        int tok = tok_s[d ? (TT - 1) : 0];
        const float* pr = P + (size_t)tok * NC + cb;
        xz_n = pr[q]; xr_n = pr[HH + q]; xh_n = pr[2 * HH + q];
    }

    int cur = 0;
    for (int i = 0; i < TT; ++i) {
        const int tcur = d ? (TT - 1 - i) : i;
        const float xz = xz_n, xr = xr_n, xh = xh_n;
        {   // prefetch next step (last iter re-reads same row; harmless)
            int in1 = (i + 1 < TT) ? (i + 1) : i;
            int tok = tok_s[d ? (TT - 1 - in1) : in1];
            const float* pr = P + (size_t)tok * NC + cb;
            xz_n = pr[q]; xr_n = pr[HH + q]; xh_n = pr[2 * HH + q];
        }

        // this lane's 32-k h slice: 16 half2 = 64 B = 4 x ds_read_b128
        half2_t hv[16];
        {
            const float4* hp = (const float4*)&hs[cur][s * 32];
            *(float4*)&hv[0]  = hp[0];
            *(float4*)&hv[4]  = hp[1];
            *(float4*)&hv[8]  = hp[2];
            *(float4*)&hv[12] = hp[3];
        }
        float az = 0.f, ar = 0.f, ah = 0.f;
        #pragma unroll
        for (int k2 = 0; k2 < 16; ++k2) {
            az = __builtin_amdgcn_fdot2(hv[k2], uz2[k2], az, false);
            ar = __builtin_amdgcn_fdot2(hv[k2], ur2[k2], ar, false);
            ah = __builtin_amdgcn_fdot2(hv[k2], uh2[k2], ah, false);
        }
        // quad butterfly: all 4 lanes end with the full sums for col q
        az = qp_add<0xB1>(az); az = qp_add<0x4E>(az);
        ar = qp_add<0xB1>(ar); ar = qp_add<0x4E>(ar);
        ah = qp_add<0xB1>(ah); ah = qp_add<0x4E>(ah);

        // gates (fp32, redundant across quad)
        float z = __builtin_amdgcn_rcpf(1.f + __expf(-(az + bz + xz)));
        float r = __builtin_amdgcn_rcpf(1.f + __expf(-(ar + br + xr)));
        float ph = xh + r * (ah + bh);
        ph = fminf(fmaxf(ph, -15.f), 15.f);
        float e  = __expf(-2.f * ph);
        float hh = (1.f - e) * __builtin_amdgcn_rcpf(1.f + e);      // tanh
        float hn = z * hreg + (1.f - z) * hh;
        hreg = hn;

        const int nxt = cur ^ 1;
        if (s == 0) {
            hs[nxt][q] = (half_t)hn;
            out[((size_t)b * TT + tcur) * 256 + d * HH + q] = hn;
        }
        BAR();           // hs[nxt] visible; all reads of hs[cur] complete
        cur = nxt;
    }

    if (s == 0) {
        // final states: [B*T*256 | h_f (B*H) | h_b (B*H)]
        out[(size_t)BB * TT * 256 + (size_t)d * BB * HH + b * HH + q] = hreg;
    }
}

// ---------------------------------------------------------------------------
extern "C" void kernel_launch(void* const* d_in, const int* in_sizes, int n_in,
                              void* d_out, int out_size, void* d_ws, size_t ws_size,
                              hipStream_t stream)
{
    const int*   tokens  = (const int*)  d_in[0];
    const float* state_f = (const float*)d_in[1];
    const float* state_b = (const float*)d_in[2];
    const float* emb     = (const float*)d_in[3];
    const float* W_f     = (const float*)d_in[4];
    const float* U_f     = (const float*)d_in[5];
    const float* b_f     = (const float*)d_in[6];
    const float* W_b     = (const float*)d_in[7];
    const float* U_b     = (const float*)d_in[8];
    const float* b_b     = (const float*)d_in[9];
    float*       out     = (float*)d_out;

    float* P = (float*)d_ws;   // needs 32000*768*4 = 98.3 MB of workspace

    dim3 gp(VV / 128, NC / 128);           // 250 x 6
    proj_kernel<<<gp, 256, 0, stream>>>(emb, W_f, W_b, b_f, b_b, P);

    dim3 gs(BB, 2);                         // 128 batch x 2 directions
    scan_kernel<<<gs, 512, 0, stream>>>(tokens, state_f, state_b,
                                        U_f, U_b, b_f, b_b, P, out);
}